// Round 1
// baseline (9874.865 us; speedup 1.0000x reference)
//
#include <hip/hip_runtime.h>
#include <hip/hip_fp16.h>

#define VOCAB 32000
#define EMB   256
#define HID   512
#define NOUT  128
#define SEQ   1024
#define NB    64

typedef _Float16 half2v __attribute__((ext_vector_type(2)));

__device__ __forceinline__ float dot2f(unsigned int w, unsigned int h, float acc) {
#if __has_builtin(__builtin_amdgcn_fdot2)
    return __builtin_amdgcn_fdot2(__builtin_bit_cast(half2v, w),
                                  __builtin_bit_cast(half2v, h), acc, false);
#else
    half2v a = __builtin_bit_cast(half2v, w);
    half2v b = __builtin_bit_cast(half2v, h);
    acc += (float)a[0] * (float)b[0];
    acc += (float)a[1] * (float)b[1];
    return acc;
#endif
}

__device__ __forceinline__ float tanh_fast(float x) {
    // tanh(x) = 1 - 2/(exp(2x)+1); exact limits at +-inf
    return 1.0f - 2.0f / (__expf(2.0f * x) + 1.0f);
}

__device__ __forceinline__ unsigned int pack_h2(float a, float b) {
    unsigned int lo = (unsigned int)__half_as_ushort(__float2half_rn(a));
    unsigned int hi = (unsigned int)__half_as_ushort(__float2half_rn(b));
    return lo | (hi << 16);
}

// ---------------------------------------------------------------------------
// Pack weights to f16 pairs, K-major (transposed) for coalesced streaming.
// whh1T[kp*512 + j] = (W_hh1[j][2kp], W_hh1[j][2kp+1])  kp<256, j<512
// wih2T[kp*128 + j] = (W_ih2[j][2kp], W_ih2[j][2kp+1])  kp<256, j<128
// whh2T[kp*128 + j] = (W_hh2[j][2kp], W_hh2[j][2kp+1])  kp<64,  j<128
// ---------------------------------------------------------------------------
__global__ void k_pack(const float* __restrict__ Whh1, const float* __restrict__ Wih2,
                       const float* __restrict__ Whh2,
                       unsigned int* __restrict__ whh1T, unsigned int* __restrict__ wih2T,
                       unsigned int* __restrict__ whh2T) {
    int gid = blockIdx.x * 256 + threadIdx.x;
    if (gid < 131072) {
        int kp = gid >> 9, j = gid & 511;
        whh1T[gid] = pack_h2(Whh1[j * 512 + 2 * kp], Whh1[j * 512 + 2 * kp + 1]);
    } else if (gid < 131072 + 32768) {
        int w = gid - 131072;
        int kp = w >> 7, j = w & 127;
        wih2T[w] = pack_h2(Wih2[j * 512 + 2 * kp], Wih2[j * 512 + 2 * kp + 1]);
    } else if (gid < 131072 + 32768 + 8192) {
        int w = gid - 163840;
        int kp = w >> 7, j = w & 127;
        whh2T[w] = pack_h2(Whh2[j * 128 + 2 * kp], Whh2[j * 128 + 2 * kp + 1]);
    }
}

// ---------------------------------------------------------------------------
// pre1[(t*64+b)][n] = sum_k emb[x[b][t]][k] * W_ih1[n][k] + b_ih1[n] + b_hh1[n]
// f32 tiled GEMM with embedding gather. BM=64 rows, BN=256 cols, BK=32.
// 256 threads, 8x8 register tile.
// ---------------------------------------------------------------------------
__global__ __launch_bounds__(256, 2) void k_gemmA(const int* __restrict__ x,
                                                  const float* __restrict__ emb,
                                                  const float* __restrict__ W,
                                                  const float* __restrict__ b1,
                                                  const float* __restrict__ b2,
                                                  float* __restrict__ pre1) {
    __shared__ float At[32][64];
    __shared__ float Bt[32][256];
    const int m0 = blockIdx.x * 64;
    const int n0 = blockIdx.y * 256;
    const int tid = threadIdx.x;
    const int tx = tid & 31, ty = tid >> 5;
    float acc[8][8] = {};

    for (int k0 = 0; k0 < EMB; k0 += 32) {
        // stage A (gathered embedding rows), transposed into LDS
        #pragma unroll
        for (int it = 0; it < 2; ++it) {
            int s = it * 256 + tid;           // 512 float4 loads
            int m = s >> 3, kg = s & 7;
            int mg = m0 + m;
            int tok = x[(mg & 63) * SEQ + (mg >> 6)];
            const float4 v = *(const float4*)(emb + (size_t)tok * EMB + k0 + kg * 4);
            At[kg * 4 + 0][m] = v.x; At[kg * 4 + 1][m] = v.y;
            At[kg * 4 + 2][m] = v.z; At[kg * 4 + 3][m] = v.w;
        }
        // stage B (W_ih1 rows n0..n0+255)
        #pragma unroll
        for (int it = 0; it < 8; ++it) {
            int s = it * 256 + tid;           // 2048 float4 loads
            int n = s >> 3, kg = s & 7;
            const float4 v = *(const float4*)(W + (size_t)(n0 + n) * EMB + k0 + kg * 4);
            Bt[kg * 4 + 0][n] = v.x; Bt[kg * 4 + 1][n] = v.y;
            Bt[kg * 4 + 2][n] = v.z; Bt[kg * 4 + 3][n] = v.w;
        }
        __syncthreads();
        #pragma unroll 4
        for (int k = 0; k < 32; ++k) {
            const float4 a0 = *(const float4*)&At[k][ty * 8];
            const float4 a1 = *(const float4*)&At[k][ty * 8 + 4];
            const float4 b0v = *(const float4*)&Bt[k][tx * 8];
            const float4 b1v = *(const float4*)&Bt[k][tx * 8 + 4];
            const float av[8] = {a0.x, a0.y, a0.z, a0.w, a1.x, a1.y, a1.z, a1.w};
            const float bv[8] = {b0v.x, b0v.y, b0v.z, b0v.w, b1v.x, b1v.y, b1v.z, b1v.w};
            #pragma unroll
            for (int i = 0; i < 8; ++i)
                #pragma unroll
                for (int j = 0; j < 8; ++j)
                    acc[i][j] = fmaf(av[i], bv[j], acc[i][j]);
        }
        __syncthreads();
    }

    const int nb = n0 + tx * 8;
    float bias[8];
    #pragma unroll
    for (int j = 0; j < 8; ++j) bias[j] = b1[nb + j] + b2[nb + j];
    #pragma unroll
    for (int i = 0; i < 8; ++i) {
        int mg = m0 + ty * 8 + i;
        float* dst = pre1 + (size_t)mg * HID + nb;
        float4 o0 = {acc[i][0] + bias[0], acc[i][1] + bias[1], acc[i][2] + bias[2], acc[i][3] + bias[3]};
        float4 o1 = {acc[i][4] + bias[4], acc[i][5] + bias[5], acc[i][6] + bias[6], acc[i][7] + bias[7]};
        *(float4*)dst = o0;
        *(float4*)(dst + 4) = o1;
    }
}

// ---------------------------------------------------------------------------
// Fused scan: layer1 recurrence + layer2 recurrence + softmax.
// 64 blocks (one batch each) x 512 threads (8 waves).
// Layer1: thread (g=tid>>3, ks=tid&7) computes cols g*8..g*8+7 over kp in
//         [ks*32, ks*32+32); 8-lane butterfly reduce; final col == tid.
// Layer2: same (g,ks); cols 2g,2g+1; W_ih2/W_hh2 f16-packed resident in VGPRs.
// h buffers in LDS as f16 pairs; h1 pair-words padded (stride 36 per 32) to
// avoid 8-way bank conflicts while keeping 16B alignment for b128 reads.
// ---------------------------------------------------------------------------
__global__ __launch_bounds__(512, 2) void k_scan(const float* __restrict__ pre1,
                                                 const unsigned int* __restrict__ whh1T,
                                                 const unsigned int* __restrict__ wih2T,
                                                 const unsigned int* __restrict__ whh2T,
                                                 const float* __restrict__ b_ih2,
                                                 const float* __restrict__ b_hh2,
                                                 float* __restrict__ out) {
    __shared__ __align__(16) unsigned short h1h[2][576]; // 288 padded pair-words per buf
    __shared__ __align__(16) unsigned short h2h[2][128]; // 64 pair-words per buf
    __shared__ __align__(16) float h2f[2][128];

    const int tid = threadIdx.x;
    const int b = blockIdx.x;
    const int ks = tid & 7;
    const int g = tid >> 3;

    // resident layer-2 weights (f16 pairs)
    unsigned int wih2r[64];
    #pragma unroll
    for (int r = 0; r < 32; ++r) {
        int kp = ks * 32 + r;
        wih2r[2 * r]     = wih2T[kp * 128 + 2 * g];
        wih2r[2 * r + 1] = wih2T[kp * 128 + 2 * g + 1];
    }
    unsigned int whh2r[16];
    #pragma unroll
    for (int r = 0; r < 8; ++r) {
        int kp = ks * 8 + r;
        whh2r[2 * r]     = whh2T[kp * 128 + 2 * g];
        whh2r[2 * r + 1] = whh2T[kp * 128 + 2 * g + 1];
    }
    const float bias2a = b_ih2[2 * g] + b_hh2[2 * g];
    const float bias2b = b_ih2[2 * g + 1] + b_hh2[2 * g + 1];

    // zero initial hidden states (t=0 reads buffer 0)
    if (tid < 288) ((unsigned int*)&h1h[0][0])[tid] = 0u;
    if (tid < 64)  ((unsigned int*)&h2h[0][0])[tid] = 0u;
    __syncthreads();

    const uint4* w4 = (const uint4*)whh1T; // [256][128] uint4

    for (int t = 0; t < SEQ; ++t) {
        const int cur = t & 1, nxt = cur ^ 1;
        const float p = pre1[(size_t)(t * NB + b) * HID + tid];

        // ---- layer 1: acc[c] = sum_k W_hh1[8g+c][k] * h1[k] over k-split ks
        float acc[8] = {0.f, 0.f, 0.f, 0.f, 0.f, 0.f, 0.f, 0.f};
        const uint4* h1q = (const uint4*)&h1h[cur][0];
        #pragma unroll
        for (int i = 0; i < 8; ++i) {
            uint4 hq = h1q[ks * 9 + i]; // pair-words kp = ks*32+4i .. +3 (padded stride 36)
            const unsigned int hh[4] = {hq.x, hq.y, hq.z, hq.w};
            #pragma unroll
            for (int q = 0; q < 4; ++q) {
                int kp = ks * 32 + i * 4 + q;
                uint4 wA = w4[kp * 128 + 2 * g];
                uint4 wB = w4[kp * 128 + 2 * g + 1];
                acc[0] = dot2f(wA.x, hh[q], acc[0]);
                acc[1] = dot2f(wA.y, hh[q], acc[1]);
                acc[2] = dot2f(wA.z, hh[q], acc[2]);
                acc[3] = dot2f(wA.w, hh[q], acc[3]);
                acc[4] = dot2f(wB.x, hh[q], acc[4]);
                acc[5] = dot2f(wB.y, hh[q], acc[5]);
                acc[6] = dot2f(wB.z, hh[q], acc[6]);
                acc[7] = dot2f(wB.w, hh[q], acc[7]);
            }
        }
        #pragma unroll
        for (int d = 1; d < 8; d <<= 1)
            #pragma unroll
            for (int c = 0; c < 8; ++c)
                acc[c] += __shfl_xor(acc[c], d, 64);
        // pick own column (col = g*8 + ks == tid)
        float s01 = (ks & 1) ? acc[1] : acc[0];
        float s23 = (ks & 1) ? acc[3] : acc[2];
        float s45 = (ks & 1) ? acc[5] : acc[4];
        float s67 = (ks & 1) ? acc[7] : acc[6];
        float s03 = (ks & 2) ? s23 : s01;
        float s47 = (ks & 2) ? s67 : s45;
        float y = ((ks & 4) ? s47 : s03) + p;
        float h1v = tanh_fast(y);
        {
            int kp = tid >> 1;
            int wq = kp + 4 * (kp >> 5); // padded word index
            h1h[nxt][2 * wq + (tid & 1)] = __half_as_ushort(__float2half_rn(h1v));
        }
        __syncthreads();

        // ---- layer 2: cols 2g, 2g+1
        float a2A = 0.f, a2B = 0.f;
        const uint4* h1qn = (const uint4*)&h1h[nxt][0];
        #pragma unroll
        for (int i = 0; i < 8; ++i) {
            uint4 hq = h1qn[ks * 9 + i];
            const unsigned int* wr = &wih2r[8 * i];
            a2A = dot2f(wr[0], hq.x, a2A);  a2B = dot2f(wr[1], hq.x, a2B);
            a2A = dot2f(wr[2], hq.y, a2A);  a2B = dot2f(wr[3], hq.y, a2B);
            a2A = dot2f(wr[4], hq.z, a2A);  a2B = dot2f(wr[5], hq.z, a2B);
            a2A = dot2f(wr[6], hq.w, a2A);  a2B = dot2f(wr[7], hq.w, a2B);
        }
        {
            const uint4* h2q = (const uint4*)&h2h[cur][0];
            uint4 hq0 = h2q[ks * 2], hq1 = h2q[ks * 2 + 1];
            a2A = dot2f(whh2r[0], hq0.x, a2A);   a2B = dot2f(whh2r[1], hq0.x, a2B);
            a2A = dot2f(whh2r[2], hq0.y, a2A);   a2B = dot2f(whh2r[3], hq0.y, a2B);
            a2A = dot2f(whh2r[4], hq0.z, a2A);   a2B = dot2f(whh2r[5], hq0.z, a2B);
            a2A = dot2f(whh2r[6], hq0.w, a2A);   a2B = dot2f(whh2r[7], hq0.w, a2B);
            a2A = dot2f(whh2r[8], hq1.x, a2A);   a2B = dot2f(whh2r[9], hq1.x, a2B);
            a2A = dot2f(whh2r[10], hq1.y, a2A);  a2B = dot2f(whh2r[11], hq1.y, a2B);
            a2A = dot2f(whh2r[12], hq1.z, a2A);  a2B = dot2f(whh2r[13], hq1.z, a2B);
            a2A = dot2f(whh2r[14], hq1.w, a2A);  a2B = dot2f(whh2r[15], hq1.w, a2B);
        }
        #pragma unroll
        for (int d = 1; d < 8; d <<= 1) {
            a2A += __shfl_xor(a2A, d, 64);
            a2B += __shfl_xor(a2B, d, 64);
        }
        if (ks < 2) {
            int cc = 2 * g + ks;
            float y2 = (ks ? a2B : a2A) + (ks ? bias2b : bias2a);
            float h2v = tanh_fast(y2);
            h2f[cur][cc] = h2v;
            h2h[nxt][cc] = __half_as_ushort(__float2half_rn(h2v));
        }
        __syncthreads();

        // ---- softmax over the 128 outputs (all waves compute; wave 0 stores)
        {
            int lane = tid & 63;
            float v0 = h2f[cur][lane];
            float v1 = h2f[cur][lane + 64];
            float m = fmaxf(v0, v1);
            #pragma unroll
            for (int d = 1; d < 64; d <<= 1) m = fmaxf(m, __shfl_xor(m, d, 64));
            float e0 = __expf(v0 - m), e1 = __expf(v1 - m);
            float s = e0 + e1;
            #pragma unroll
            for (int d = 1; d < 64; d <<= 1) s += __shfl_xor(s, d, 64);
            if (tid < 64) {
                out[(size_t)b * (NOUT * SEQ) + (size_t)lane * SEQ + t] = __fdividef(e0, s);
                out[(size_t)b * (NOUT * SEQ) + (size_t)(lane + 64) * SEQ + t] = __fdividef(e1, s);
            }
        }
    }
}

extern "C" void kernel_launch(void* const* d_in, const int* in_sizes, int n_in,
                              void* d_out, int out_size, void* d_ws, size_t ws_size,
                              hipStream_t stream) {
    const int*   x     = (const int*)d_in[0];
    const float* emb   = (const float*)d_in[1];
    const float* Wih1  = (const float*)d_in[2];
    const float* Whh1  = (const float*)d_in[3];
    const float* bih1  = (const float*)d_in[4];
    const float* bhh1  = (const float*)d_in[5];
    const float* Wih2  = (const float*)d_in[6];
    const float* Whh2  = (const float*)d_in[7];
    const float* bih2  = (const float*)d_in[8];
    const float* bhh2  = (const float*)d_in[9];
    float* out = (float*)d_out;

    unsigned int* whh1T = (unsigned int*)d_ws;          // 131072 u32
    unsigned int* wih2T = whh1T + 131072;               // 32768 u32
    unsigned int* whh2T = wih2T + 32768;                // 8192 u32
    float* pre1 = (float*)(whh2T + 8192);               // 65536*512 f32 (~134 MB)

    k_pack<<<672, 256, 0, stream>>>(Whh1, Wih2, Whh2, whh1T, wih2T, whh2T);

    dim3 gA(65536 / 64, 2);
    k_gemmA<<<gA, 256, 0, stream>>>(x, emb, Wih1, bih1, bhh1, pre1);

    k_scan<<<64, 512, 0, stream>>>(pre1, whh1T, wih2T, whh2T, bih2, bhh2, out);
}

// Round 2
// 9503.823 us; speedup vs baseline: 1.0390x; 1.0390x over previous
//
#include <hip/hip_runtime.h>
#include <hip/hip_fp16.h>

#define VOCAB 32000
#define EMB   256
#define HID   512
#define NOUT  128
#define SEQ   1024
#define NB    64

typedef _Float16 half2v __attribute__((ext_vector_type(2)));

__device__ __forceinline__ float dot2f(unsigned int w, unsigned int h, float acc) {
#if __has_builtin(__builtin_amdgcn_fdot2)
    return __builtin_amdgcn_fdot2(__builtin_bit_cast(half2v, w),
                                  __builtin_bit_cast(half2v, h), acc, false);
#else
    half2v a = __builtin_bit_cast(half2v, w);
    half2v b = __builtin_bit_cast(half2v, h);
    acc += (float)a[0] * (float)b[0];
    acc += (float)a[1] * (float)b[1];
    return acc;
#endif
}

__device__ __forceinline__ float tanh_fast(float x) {
    return 1.0f - 2.0f / (__expf(2.0f * x) + 1.0f);
}

__device__ __forceinline__ unsigned int pack_h2(float a, float b) {
    unsigned int lo = (unsigned int)__half_as_ushort(__float2half_rn(a));
    unsigned int hi = (unsigned int)__half_as_ushort(__float2half_rn(b));
    return lo | (hi << 16);
}

// ---------------------------------------------------------------------------
// Pack weights to f16 pairs, K-major; also zero the exchange flags (d_ws is
// poisoned 0xAA before every timed launch, and 0xAAAAAAAA >= any t+1 would
// break the >= poll).
// whh1T[kp*512 + j] = (W_hh1[j][2kp], W_hh1[j][2kp+1])  kp<256, j<512
// wih2T[kp*128 + j] = (W_ih2[j][2kp], W_ih2[j][2kp+1])  kp<256, j<128
// whh2T[kp*128 + j] = (W_hh2[j][2kp], W_hh2[j][2kp+1])  kp<64,  j<128
// ---------------------------------------------------------------------------
__global__ void k_pack(const float* __restrict__ Whh1, const float* __restrict__ Wih2,
                       const float* __restrict__ Whh2,
                       unsigned int* __restrict__ whh1T, unsigned int* __restrict__ wih2T,
                       unsigned int* __restrict__ whh2T, unsigned int* __restrict__ xflags) {
    int gid = blockIdx.x * 256 + threadIdx.x;
    if (gid < 4096) xflags[gid] = 0u;   // 64 batches x 4 quarters x 16-word (64B) stride
    if (gid < 131072) {
        int kp = gid >> 9, j = gid & 511;
        whh1T[gid] = pack_h2(Whh1[j * 512 + 2 * kp], Whh1[j * 512 + 2 * kp + 1]);
    } else if (gid < 131072 + 32768) {
        int w = gid - 131072;
        int kp = w >> 7, j = w & 127;
        wih2T[w] = pack_h2(Wih2[j * 512 + 2 * kp], Wih2[j * 512 + 2 * kp + 1]);
    } else if (gid < 131072 + 32768 + 8192) {
        int w = gid - 163840;
        int kp = w >> 7, j = w & 127;
        whh2T[w] = pack_h2(Whh2[j * 128 + 2 * kp], Whh2[j * 128 + 2 * kp + 1]);
    }
}

// ---------------------------------------------------------------------------
// pre1[(t*64+b)][n] = sum_k emb[x[b][t]][k] * W_ih1[n][k] + b_ih1[n] + b_hh1[n]
// f32 tiled GEMM with embedding gather (unchanged from R0).
// ---------------------------------------------------------------------------
__global__ __launch_bounds__(256, 2) void k_gemmA(const int* __restrict__ x,
                                                  const float* __restrict__ emb,
                                                  const float* __restrict__ W,
                                                  const float* __restrict__ b1,
                                                  const float* __restrict__ b2,
                                                  float* __restrict__ pre1) {
    __shared__ float At[32][64];
    __shared__ float Bt[32][256];
    const int m0 = blockIdx.x * 64;
    const int n0 = blockIdx.y * 256;
    const int tid = threadIdx.x;
    const int tx = tid & 31, ty = tid >> 5;
    float acc[8][8] = {};

    for (int k0 = 0; k0 < EMB; k0 += 32) {
        #pragma unroll
        for (int it = 0; it < 2; ++it) {
            int s = it * 256 + tid;
            int m = s >> 3, kg = s & 7;
            int mg = m0 + m;
            int tok = x[(mg & 63) * SEQ + (mg >> 6)];
            const float4 v = *(const float4*)(emb + (size_t)tok * EMB + k0 + kg * 4);
            At[kg * 4 + 0][m] = v.x; At[kg * 4 + 1][m] = v.y;
            At[kg * 4 + 2][m] = v.z; At[kg * 4 + 3][m] = v.w;
        }
        #pragma unroll
        for (int it = 0; it < 8; ++it) {
            int s = it * 256 + tid;
            int n = s >> 3, kg = s & 7;
            const float4 v = *(const float4*)(W + (size_t)(n0 + n) * EMB + k0 + kg * 4);
            Bt[kg * 4 + 0][n] = v.x; Bt[kg * 4 + 1][n] = v.y;
            Bt[kg * 4 + 2][n] = v.z; Bt[kg * 4 + 3][n] = v.w;
        }
        __syncthreads();
        #pragma unroll 4
        for (int k = 0; k < 32; ++k) {
            const float4 a0 = *(const float4*)&At[k][ty * 8];
            const float4 a1 = *(const float4*)&At[k][ty * 8 + 4];
            const float4 b0v = *(const float4*)&Bt[k][tx * 8];
            const float4 b1v = *(const float4*)&Bt[k][tx * 8 + 4];
            const float av[8] = {a0.x, a0.y, a0.z, a0.w, a1.x, a1.y, a1.z, a1.w};
            const float bv[8] = {b0v.x, b0v.y, b0v.z, b0v.w, b1v.x, b1v.y, b1v.z, b1v.w};
            #pragma unroll
            for (int i = 0; i < 8; ++i)
                #pragma unroll
                for (int j = 0; j < 8; ++j)
                    acc[i][j] = fmaf(av[i], bv[j], acc[i][j]);
        }
        __syncthreads();
    }

    const int nb = n0 + tx * 8;
    float bias[8];
    #pragma unroll
    for (int j = 0; j < 8; ++j) bias[j] = b1[nb + j] + b2[nb + j];
    #pragma unroll
    for (int i = 0; i < 8; ++i) {
        int mg = m0 + ty * 8 + i;
        float* dst = pre1 + (size_t)mg * HID + nb;
        float4 o0 = {acc[i][0] + bias[0], acc[i][1] + bias[1], acc[i][2] + bias[2], acc[i][3] + bias[3]};
        float4 o1 = {acc[i][4] + bias[4], acc[i][5] + bias[5], acc[i][6] + bias[6], acc[i][7] + bias[7]};
        *(float4*)dst = o0;
        *(float4*)(dst + 4) = o1;
    }
}

// ---------------------------------------------------------------------------
// Fused scan v2: 256 blocks = 64 batches x 4 quarter-slices, one block/CU.
// Block (b, q): q-th 128-row slice of layer-1; layer-2 + softmax computed
// redundantly in all 4 blocks (each writes its 32 output rows).
// ALL weights register-resident (144 u32/thread of f16 pairs):
//   w1r: W_hh1 rows [128q..128q+128) x k-quarter s     (64 regs)
//   w2r: W_ih2 rows j x k-quarter s                     (64 regs)
//   w3r: W_hh2 rows j x k-quarter s                     (16 regs)
// Thread (j = tid>>2, s = tid&3); 4-lane shfl_xor reduction over s.
// Per-step h1-slice exchange through global xbuf (parity double-buffered)
// with monotonic flags: release = syncthreads(vmcnt drain) + threadfence +
// relaxed agent store; acquire = relaxed agent poll + threadfence. Correct
// for any XCD placement; group {b,b+64,b+128,b+192} = same XCD empirically.
// Layer-2(t-1) compute fills the poll window. Outputs staged 16 steps in
// LDS, flushed as full 64B lines (kills the 18x WRITE_SIZE inflation).
// __launch_bounds__(512,2): <=256 VGPR -> exactly one block/CU -> 256 blocks
// on 256 CUs are all co-resident (spin cannot deadlock).
// ---------------------------------------------------------------------------
__global__ __launch_bounds__(512, 2) void k_scan(
    const float* __restrict__ pre1,
    const unsigned int* __restrict__ whh1T,
    const unsigned int* __restrict__ wih2T,
    const unsigned int* __restrict__ whh2T,
    const float* __restrict__ b_ih2,
    const float* __restrict__ b_hh2,
    unsigned int* xflags,
    unsigned int* xbuf,
    float* __restrict__ out) {

    // h1 as f16 pairs, 4 chunks of 64 u32 padded to 68 (17 uint4) so the
    // 4 distinct per-wave b128 addresses hit distinct banks.
    __shared__ __align__(16) unsigned int h1w[4 * 68];
    __shared__ __align__(16) unsigned int h2w[2 * 64];   // h2 f16 pairs, double buffered
    __shared__ float h2f[128];                           // h2 f32 for softmax
    __shared__ float ostage[32][17];                     // 16-step output staging (+pad)

    const int tid = threadIdx.x;
    const int bid = blockIdx.x;
    const int b = bid & 63;
    const int q = bid >> 6;
    const int j = tid >> 2;        // output row within slice / layer-2 row
    const int s = tid & 3;         // k-quarter
    const int n = 128 * q + j;     // global layer-1 row

    unsigned int w1r[64], w2r[64], w3r[16];
    #pragma unroll
    for (int r = 0; r < 64; ++r) w1r[r] = whh1T[(64 * s + r) * 512 + n];
    #pragma unroll
    for (int r = 0; r < 64; ++r) w2r[r] = wih2T[(64 * s + r) * 128 + j];
    #pragma unroll
    for (int r = 0; r < 16; ++r) w3r[r] = whh2T[(16 * s + r) * 128 + j];
    const float bias2 = b_ih2[j] + b_hh2[j];

    if (tid < 272) h1w[tid] = 0u;      // h1[-1] = 0
    if (tid < 128) h2w[tid] = 0u;      // h2[-1] = 0 (both parities)
    __syncthreads();

    unsigned short h16 = 0;

    for (int t = 0; t < SEQ; ++t) {
        const int par = t & 1;

        // ---- phase 1: layer-1(t) from h1w (= h1[t-1])
        float pre = 0.f;
        if (s == 0) pre = pre1[(size_t)(t * NB + b) * HID + n];
        float acc = 0.f;
        const uint4* hq4 = (const uint4*)h1w;
        #pragma unroll
        for (int i = 0; i < 16; ++i) {
            uint4 h = hq4[s * 17 + i];
            acc = dot2f(w1r[4 * i + 0], h.x, acc);
            acc = dot2f(w1r[4 * i + 1], h.y, acc);
            acc = dot2f(w1r[4 * i + 2], h.z, acc);
            acc = dot2f(w1r[4 * i + 3], h.w, acc);
        }
        acc += __shfl_xor(acc, 1, 64);
        acc += __shfl_xor(acc, 2, 64);
        if (s == 0) {
            float h1v = tanh_fast(acc + pre);
            h16 = __half_as_ushort(__float2half_rn(h1v));
            // publish own slice element (u16) to the parity buffer
            ((unsigned short*)xbuf)[(par * 256 + b * 4 + q) * 128 + j] = h16;
        }
        __syncthreads();   // B1: compiler drains vmcnt per wave -> slice in L2

        // ---- phase 3: wave 0 handles release->flag->poll->acquire
        if (tid < 64) {
            if (tid == 0) {
                __threadfence();   // release: L2 writeback to coherence point
                __hip_atomic_store(&xflags[(b * 4 + q) * 16], (unsigned int)(t + 1),
                                   __ATOMIC_RELAXED, __HIP_MEMORY_SCOPE_AGENT);
            }
            if (tid < 3) {
                int qq = (q + 1 + tid) & 3;
                const unsigned int* fp = &xflags[(b * 4 + qq) * 16];
                while (__hip_atomic_load(fp, __ATOMIC_RELAXED, __HIP_MEMORY_SCOPE_AGENT)
                       < (unsigned int)(t + 1)) {}
            }
            __threadfence();       // acquire: invalidate L1/L2 shadow before reads
        }
        // layer-2(t-1) partial meanwhile (reads h1w = h1[t-1], h2w[par] = h2[t-2])
        if (t > 0) {
            float a2 = 0.f;
            #pragma unroll
            for (int i = 0; i < 16; ++i) {
                uint4 h = hq4[s * 17 + i];
                a2 = dot2f(w2r[4 * i + 0], h.x, a2);
                a2 = dot2f(w2r[4 * i + 1], h.y, a2);
                a2 = dot2f(w2r[4 * i + 2], h.z, a2);
                a2 = dot2f(w2r[4 * i + 3], h.w, a2);
            }
            const uint4* g2 = (const uint4*)(h2w + par * 64);
            #pragma unroll
            for (int i = 0; i < 4; ++i) {
                uint4 h = g2[s * 4 + i];
                a2 = dot2f(w3r[4 * i + 0], h.x, a2);
                a2 = dot2f(w3r[4 * i + 1], h.y, a2);
                a2 = dot2f(w3r[4 * i + 2], h.z, a2);
                a2 = dot2f(w3r[4 * i + 3], h.w, a2);
            }
            a2 += __shfl_xor(a2, 1, 64);
            a2 += __shfl_xor(a2, 2, 64);
            if (s == 0) {
                float h2v = tanh_fast(a2 + bias2);
                h2f[j] = h2v;
                ((unsigned short*)(h2w + (par ^ 1) * 64))[j] =
                    __half_as_ushort(__float2half_rn(h2v));
            }
        }
        __syncthreads();   // B2: poll done; all h1w[t-1] reads done

        // ---- phase 5: gather remote slices into h1w; write own from reg
        if (tid >= 64 && tid < 256) {
            int v = tid - 64, r = v >> 6, w = v & 63;
            int c = (q + 1 + r) & 3;
            h1w[c * 68 + w] = xbuf[(par * 256 + b * 4 + c) * 64 + w];
        }
        if (s == 0) ((unsigned short*)h1w)[q * 136 + j] = h16;
        // periodic output flush: full 64B lines, window t0 = t-17
        if ((t & 15) == 1 && t > 16 && tid >= 256 && tid < 384) {
            int v = tid - 256, row = v >> 2, seg = v & 3;
            int t0 = t - 17;
            float4 o;
            o.x = ostage[row][seg * 4 + 0];
            o.y = ostage[row][seg * 4 + 1];
            o.z = ostage[row][seg * 4 + 2];
            o.w = ostage[row][seg * 4 + 3];
            *(float4*)(out + (size_t)(b * NOUT + 32 * q + row) * SEQ + t0 + seg * 4) = o;
        }
        __syncthreads();   // B3: h1w = h1[t] complete; h2f complete

        // ---- phase 7: softmax(t-1) by wave 0 (others proceed to next t)
        if (t > 0 && tid < 64) {
            float v0 = h2f[2 * tid], v1 = h2f[2 * tid + 1];
            float m = fmaxf(v0, v1);
            #pragma unroll
            for (int d = 1; d < 64; d <<= 1) m = fmaxf(m, __shfl_xor(m, d, 64));
            float e0 = __expf(v0 - m), e1 = __expf(v1 - m);
            float ss = e0 + e1;
            #pragma unroll
            for (int d = 1; d < 64; d <<= 1) ss += __shfl_xor(ss, d, 64);
            if (tid >= 16 * q && tid < 16 * q + 16) {
                int rr = 2 * tid - 32 * q;
                int col = (t - 1) & 15;
                float inv = __fdividef(1.0f, ss);
                ostage[rr][col] = e0 * inv;
                ostage[rr + 1][col] = e1 * inv;
            }
        }
    }

    // ---- epilogue: layer-2(1023), softmax(1023), flush window t0 = 1008
    __syncthreads();
    {
        const int par = SEQ & 1;   // 0: h2w[0] holds h2[1022]
        float a2 = 0.f;
        const uint4* hq4 = (const uint4*)h1w;
        #pragma unroll
        for (int i = 0; i < 16; ++i) {
            uint4 h = hq4[s * 17 + i];
            a2 = dot2f(w2r[4 * i + 0], h.x, a2);
            a2 = dot2f(w2r[4 * i + 1], h.y, a2);
            a2 = dot2f(w2r[4 * i + 2], h.z, a2);
            a2 = dot2f(w2r[4 * i + 3], h.w, a2);
        }
        const uint4* g2 = (const uint4*)(h2w + par * 64);
        #pragma unroll
        for (int i = 0; i < 4; ++i) {
            uint4 h = g2[s * 4 + i];
            a2 = dot2f(w3r[4 * i + 0], h.x, a2);
            a2 = dot2f(w3r[4 * i + 1], h.y, a2);
            a2 = dot2f(w3r[4 * i + 2], h.z, a2);
            a2 = dot2f(w3r[4 * i + 3], h.w, a2);
        }
        a2 += __shfl_xor(a2, 1, 64);
        a2 += __shfl_xor(a2, 2, 64);
        if (s == 0) h2f[j] = tanh_fast(a2 + bias2);
    }
    __syncthreads();
    if (tid < 64) {
        float v0 = h2f[2 * tid], v1 = h2f[2 * tid + 1];
        float m = fmaxf(v0, v1);
        #pragma unroll
        for (int d = 1; d < 64; d <<= 1) m = fmaxf(m, __shfl_xor(m, d, 64));
        float e0 = __expf(v0 - m), e1 = __expf(v1 - m);
        float ss = e0 + e1;
        #pragma unroll
        for (int d = 1; d < 64; d <<= 1) ss += __shfl_xor(ss, d, 64);
        if (tid >= 16 * q && tid < 16 * q + 16) {
            int rr = 2 * tid - 32 * q;
            float inv = __fdividef(1.0f, ss);
            ostage[rr][15] = e0 * inv;
            ostage[rr + 1][15] = e1 * inv;
        }
    }
    __syncthreads();
    if (tid < 128) {
        int row = tid >> 2, seg = tid & 3;
        int t0 = SEQ - 16;
        float4 o;
        o.x = ostage[row][seg * 4 + 0];
        o.y = ostage[row][seg * 4 + 1];
        o.z = ostage[row][seg * 4 + 2];
        o.w = ostage[row][seg * 4 + 3];
        *(float4*)(out + (size_t)(b * NOUT + 32 * q + row) * SEQ + t0 + seg * 4) = o;
    }
}

extern "C" void kernel_launch(void* const* d_in, const int* in_sizes, int n_in,
                              void* d_out, int out_size, void* d_ws, size_t ws_size,
                              hipStream_t stream) {
    const int*   x     = (const int*)d_in[0];
    const float* emb   = (const float*)d_in[1];
    const float* Wih1  = (const float*)d_in[2];
    const float* Whh1  = (const float*)d_in[3];
    const float* bih1  = (const float*)d_in[4];
    const float* bhh1  = (const float*)d_in[5];
    const float* Wih2  = (const float*)d_in[6];
    const float* Whh2  = (const float*)d_in[7];
    const float* bih2  = (const float*)d_in[8];
    const float* bhh2  = (const float*)d_in[9];
    float* out = (float*)d_out;

    unsigned int* whh1T  = (unsigned int*)d_ws;          // 131072 u32 (512 KB)
    unsigned int* wih2T  = whh1T + 131072;               // 32768 u32 (128 KB)
    unsigned int* whh2T  = wih2T + 32768;                // 8192 u32  (32 KB)
    unsigned int* xflags = whh2T + 8192;                 // 4096 u32  (16 KB)
    unsigned int* xbuf   = xflags + 4096;                // 32768 u32 (128 KB)
    float* pre1 = (float*)(xbuf + 32768);                // 65536*512 f32 (~134 MB)

    k_pack<<<672, 256, 0, stream>>>(Whh1, Wih2, Whh2, whh1T, wih2T, whh2T, xflags);

    dim3 gA(65536 / 64, 2);
    k_gemmA<<<gA, 256, 0, stream>>>(x, emb, Wih1, bih1, bhh1, pre1);

    k_scan<<<256, 512, 0, stream>>>(pre1, whh1T, wih2T, whh2T, bih2, bhh2,
                                    xflags, xbuf, out);
}

// Round 3
// 3157.776 us; speedup vs baseline: 3.1272x; 3.0097x over previous
//
#include <hip/hip_runtime.h>
#include <hip/hip_fp16.h>

#define VOCAB 32000
#define EMB   256
#define HID   512
#define NOUT  128
#define SEQ   1024
#define NB    64
#define WPB   96   // exchange payload words per block/step: 64 h1-pairs + 32 h2-f32

typedef _Float16 half2v __attribute__((ext_vector_type(2)));

__device__ __forceinline__ float dot2f(unsigned int w, unsigned int h, float acc) {
#if __has_builtin(__builtin_amdgcn_fdot2)
    return __builtin_amdgcn_fdot2(__builtin_bit_cast(half2v, w),
                                  __builtin_bit_cast(half2v, h), acc, false);
#else
    half2v a = __builtin_bit_cast(half2v, w);
    half2v b = __builtin_bit_cast(half2v, h);
    acc += (float)a[0] * (float)b[0];
    acc += (float)a[1] * (float)b[1];
    return acc;
#endif
}

__device__ __forceinline__ float tanh_fast(float x) {
    return 1.0f - 2.0f / (__expf(2.0f * x) + 1.0f);
}

__device__ __forceinline__ unsigned int pack_h2(float a, float b) {
    unsigned int lo = (unsigned int)__half_as_ushort(__float2half_rn(a));
    unsigned int hi = (unsigned int)__half_as_ushort(__float2half_rn(b));
    return lo | (hi << 16);
}

// ---------------------------------------------------------------------------
// Pack weights to f16 pairs, K-major. Zero exchange flags with AGENT-scope
// stores (k_scan polls them with sc1 loads that bypass local L2).
// whh1T[p*512 + n] = (W_hh1[n][2p], W_hh1[n][2p+1])   p<256, n<512
// wih2T[p*128 + j] = (W_ih2[j][2p], W_ih2[j][2p+1])   p<256, j<128
// whh2T[p*128 + j] = (W_hh2[j][2p], W_hh2[j][2p+1])   p<64,  j<128
// ---------------------------------------------------------------------------
__global__ void k_pack(const float* __restrict__ Whh1, const float* __restrict__ Wih2,
                       const float* __restrict__ Whh2,
                       unsigned int* __restrict__ whh1T, unsigned int* __restrict__ wih2T,
                       unsigned int* __restrict__ whh2T, unsigned int* __restrict__ xflags) {
    int gid = blockIdx.x * 256 + threadIdx.x;
    if (gid < 4096)
        __hip_atomic_store(&xflags[gid], 0u, __ATOMIC_RELAXED, __HIP_MEMORY_SCOPE_AGENT);
    if (gid < 131072) {
        int p = gid >> 9, n = gid & 511;
        whh1T[gid] = pack_h2(Whh1[n * 512 + 2 * p], Whh1[n * 512 + 2 * p + 1]);
    } else if (gid < 131072 + 32768) {
        int w = gid - 131072;
        int p = w >> 7, j = w & 127;
        wih2T[w] = pack_h2(Wih2[j * 512 + 2 * p], Wih2[j * 512 + 2 * p + 1]);
    } else if (gid < 131072 + 32768 + 8192) {
        int w = gid - 163840;
        int p = w >> 7, j = w & 127;
        whh2T[w] = pack_h2(Whh2[j * 128 + 2 * p], Whh2[j * 128 + 2 * p + 1]);
    }
}

// ---------------------------------------------------------------------------
// pre1 GEMM with embedding gather (unchanged from R1).
// ---------------------------------------------------------------------------
__global__ __launch_bounds__(256, 2) void k_gemmA(const int* __restrict__ x,
                                                  const float* __restrict__ emb,
                                                  const float* __restrict__ W,
                                                  const float* __restrict__ b1,
                                                  const float* __restrict__ b2,
                                                  float* __restrict__ pre1) {
    __shared__ float At[32][64];
    __shared__ float Bt[32][256];
    const int m0 = blockIdx.x * 64;
    const int n0 = blockIdx.y * 256;
    const int tid = threadIdx.x;
    const int tx = tid & 31, ty = tid >> 5;
    float acc[8][8] = {};

    for (int k0 = 0; k0 < EMB; k0 += 32) {
        #pragma unroll
        for (int it = 0; it < 2; ++it) {
            int s = it * 256 + tid;
            int m = s >> 3, kg = s & 7;
            int mg = m0 + m;
            int tok = x[(mg & 63) * SEQ + (mg >> 6)];
            const float4 v = *(const float4*)(emb + (size_t)tok * EMB + k0 + kg * 4);
            At[kg * 4 + 0][m] = v.x; At[kg * 4 + 1][m] = v.y;
            At[kg * 4 + 2][m] = v.z; At[kg * 4 + 3][m] = v.w;
        }
        #pragma unroll
        for (int it = 0; it < 8; ++it) {
            int s = it * 256 + tid;
            int n = s >> 3, kg = s & 7;
            const float4 v = *(const float4*)(W + (size_t)(n0 + n) * EMB + k0 + kg * 4);
            Bt[kg * 4 + 0][n] = v.x; Bt[kg * 4 + 1][n] = v.y;
            Bt[kg * 4 + 2][n] = v.z; Bt[kg * 4 + 3][n] = v.w;
        }
        __syncthreads();
        #pragma unroll 4
        for (int k = 0; k < 32; ++k) {
            const float4 a0 = *(const float4*)&At[k][ty * 8];
            const float4 a1 = *(const float4*)&At[k][ty * 8 + 4];
            const float4 b0v = *(const float4*)&Bt[k][tx * 8];
            const float4 b1v = *(const float4*)&Bt[k][tx * 8 + 4];
            const float av[8] = {a0.x, a0.y, a0.z, a0.w, a1.x, a1.y, a1.z, a1.w};
            const float bv[8] = {b0v.x, b0v.y, b0v.z, b0v.w, b1v.x, b1v.y, b1v.z, b1v.w};
            #pragma unroll
            for (int i = 0; i < 8; ++i)
                #pragma unroll
                for (int j = 0; j < 8; ++j)
                    acc[i][j] = fmaf(av[i], bv[j], acc[i][j]);
        }
        __syncthreads();
    }

    const int nb = n0 + tx * 8;
    float bias[8];
    #pragma unroll
    for (int j = 0; j < 8; ++j) bias[j] = b1[nb + j] + b2[nb + j];
    #pragma unroll
    for (int i = 0; i < 8; ++i) {
        int mg = m0 + ty * 8 + i;
        float* dst = pre1 + (size_t)mg * HID + nb;
        float4 o0 = {acc[i][0] + bias[0], acc[i][1] + bias[1], acc[i][2] + bias[2], acc[i][3] + bias[3]};
        float4 o1 = {acc[i][4] + bias[4], acc[i][5] + bias[5], acc[i][6] + bias[6], acc[i][7] + bias[7]};
        *(float4*)dst = o0;
        *(float4*)(dst + 4) = o1;
    }
}

__device__ __forceinline__ void softmax_store(const float* h2f, float (*ostage)[17],
                                              int q, int tid, int col) {
    // caller guards tid<64; wave0 fully active
    float v0 = h2f[2 * tid], v1 = h2f[2 * tid + 1];
    float m = fmaxf(v0, v1);
    #pragma unroll
    for (int d = 1; d < 64; d <<= 1) m = fmaxf(m, __shfl_xor(m, d, 64));
    float e0 = __expf(v0 - m), e1 = __expf(v1 - m);
    float s = e0 + e1;
    #pragma unroll
    for (int d = 1; d < 64; d <<= 1) s += __shfl_xor(s, d, 64);
    if (tid >= 16 * q && tid < 16 * q + 16) {
        int rr = 2 * tid - 32 * q;
        float inv = __fdividef(1.0f, s);
        ostage[rr][col] = e0 * inv;
        ostage[rr + 1][col] = e1 * inv;
    }
}

// ---------------------------------------------------------------------------
// Fused scan v3: 256 blocks = 64 batches x 4 slices, 1 block/CU.
// Layer-1: thread (rp=tid>>3, s8=tid&7): rows {128q+2rp, +1}, k-eighth s8.
//          w1r = 64 u32 f16 pairs. Reduce over 8 lanes.
// Layer-2: DISTRIBUTED (32 rows/block): thread (r2=tid>>4, ks2=tid&15):
//          row 32q+r2, k-sixteenth. w2r=16, w3r=4 u32. Reduce over 16 lanes.
// Exchange per step: one 384B payload {64 u32 h1-pairs, 32 f32 h2} per block,
// written/read with AGENT-scope (sc1) atomics -- NO threadfence, no cache
// maintenance. Ordering: syncthreads (vmcnt drain) -> relaxed flag store;
// per-wave 3-lane poll; compiler memory barrier; sc1 gather.
// Total resident weights: 84 u32/thread (no spill expected).
// ---------------------------------------------------------------------------
__global__ __launch_bounds__(512, 2) void k_scan(
    const float* __restrict__ pre1,
    const unsigned int* __restrict__ whh1T,
    const unsigned int* __restrict__ wih2T,
    const unsigned int* __restrict__ whh2T,
    const float* __restrict__ b_ih2,
    const float* __restrict__ b_hh2,
    unsigned int* xflags,
    unsigned int* xbuf,
    float* __restrict__ out) {

    __shared__ __align__(16) unsigned int h1w[256];  // h1 full, f16 pairs
    __shared__ __align__(16) unsigned int h2w[64];   // h2 full, f16 pairs
    __shared__ float h2f[128];                       // h2 full, f32 (softmax input)
    __shared__ float ostage[32][17];                 // 16-step output staging

    const int tid = threadIdx.x;
    const int bid = blockIdx.x;
    const int b = bid & 63;
    const int q = bid >> 6;
    const int rp = tid >> 3, s8 = tid & 7;     // layer-1 mapping
    const int r2 = tid >> 4, ks2 = tid & 15;   // layer-2 mapping
    const int R2 = 32 * q + r2;

    // ---- resident weights
    unsigned int w1r[64], w2r[16], w3r[4];
    #pragma unroll
    for (int r = 0; r < 16; ++r)
        #pragma unroll
        for (int i = 0; i < 2; ++i)
            #pragma unroll
            for (int c = 0; c < 2; ++c)
                w1r[r * 4 + i * 2 + c] =
                    whh1T[(size_t)(2 * (s8 + 8 * r) + c) * 512 + (128 * q + 2 * rp + i)];
    #pragma unroll
    for (int r = 0; r < 8; ++r)
        #pragma unroll
        for (int c = 0; c < 2; ++c)
            w2r[r * 2 + c] = wih2T[(size_t)(2 * (ks2 + 16 * r) + c) * 128 + R2];
    #pragma unroll
    for (int r = 0; r < 2; ++r)
        #pragma unroll
        for (int c = 0; c < 2; ++c)
            w3r[r * 2 + c] = whh2T[(size_t)(2 * (ks2 + 16 * r) + c) * 128 + R2];
    const float bias2 = b_ih2[R2] + b_hh2[R2];

    if (tid < 256) h1w[tid] = 0u;
    if (tid < 64)  h2w[tid] = 0u;
    __syncthreads();

    const uint2* h1q = (const uint2*)h1w;   // 128 u64 words (pairs of pairs)
    const uint2* h2q = (const uint2*)h2w;   // 32 u64 words

    for (int t = 0; t < SEQ; ++t) {
        const int par = t & 1;
        const int xb_self = ((par * NB + b) * 4 + q) * WPB;

        // ---- layer 1 (t): rows 2rp, 2rp+1; k-eighth s8
        float acc0 = 0.f, acc1 = 0.f;
        #pragma unroll
        for (int r = 0; r < 16; ++r) {
            uint2 H = h1q[s8 + 8 * r];
            acc0 = dot2f(w1r[4 * r + 0], H.x, acc0);
            acc0 = dot2f(w1r[4 * r + 1], H.y, acc0);
            acc1 = dot2f(w1r[4 * r + 2], H.x, acc1);
            acc1 = dot2f(w1r[4 * r + 3], H.y, acc1);
        }
        #pragma unroll
        for (int d = 1; d < 8; d <<= 1) {
            acc0 += __shfl_xor(acc0, d, 64);
            acc1 += __shfl_xor(acc1, d, 64);
        }
        unsigned int hp = 0u;
        if (s8 == 0) {
            float2 pr = *(const float2*)(pre1 + (size_t)(t * NB + b) * HID + 128 * q + 2 * rp);
            float h0 = tanh_fast(acc0 + pr.x);
            float h1v = tanh_fast(acc1 + pr.y);
            hp = pack_h2(h0, h1v);
            __hip_atomic_store(&xbuf[xb_self + rp], hp,
                               __ATOMIC_RELAXED, __HIP_MEMORY_SCOPE_AGENT);
        }

        // ---- layer 2 (t-1): row R2, k-sixteenth ks2 (reads h1w=h1(t-1), h2w=h2(t-2))
        float h2v = 0.f;
        if (t > 0) {
            float a2 = 0.f;
            #pragma unroll
            for (int r = 0; r < 8; ++r) {
                uint2 H = h1q[ks2 + 16 * r];
                a2 = dot2f(w2r[2 * r + 0], H.x, a2);
                a2 = dot2f(w2r[2 * r + 1], H.y, a2);
            }
            #pragma unroll
            for (int r = 0; r < 2; ++r) {
                uint2 H = h2q[ks2 + 16 * r];
                a2 = dot2f(w3r[2 * r + 0], H.x, a2);
                a2 = dot2f(w3r[2 * r + 1], H.y, a2);
            }
            #pragma unroll
            for (int d = 1; d < 16; d <<= 1) a2 += __shfl_xor(a2, d, 64);
            h2v = tanh_fast(a2 + bias2);
        }
        if (ks2 == 0)
            __hip_atomic_store(&xbuf[xb_self + 64 + r2], __float_as_uint(h2v),
                               __ATOMIC_RELAXED, __HIP_MEMORY_SCOPE_AGENT);
        float h2vp = __shfl_xor(h2v, 16, 64);   // partner row (for f16 pair pack)

        // ---- softmax(t-2) on wave0 (reads h2f = h2(t-2))
        if (t >= 2 && tid < 64) softmax_store(h2f, ostage, q, tid, (t - 2) & 15);

        __syncthreads();   // B1: all publishes drained (vmcnt 0 at barrier)

        if (tid == 0)
            __hip_atomic_store(&xflags[(b * 4 + q) * 16], (unsigned int)(t + 1),
                               __ATOMIC_RELAXED, __HIP_MEMORY_SCOPE_AGENT);

        // ---- output flush (lanes 384..511), overlaps poll+gather
        if ((t & 15) == 1 && t > 16 && tid >= 384) {
            int v = tid - 384, row = v >> 2, seg = v & 3;
            int t0 = t - 17;
            float4 o;
            o.x = ostage[row][seg * 4 + 0];
            o.y = ostage[row][seg * 4 + 1];
            o.z = ostage[row][seg * 4 + 2];
            o.w = ostage[row][seg * 4 + 3];
            *(float4*)(out + (size_t)(b * NOUT + 32 * q + row) * SEQ + t0 + seg * 4) = o;
        }

        // ---- per-wave poll (waves 0..4 hold gather lanes): 3 lanes spin,
        // exec-mask makes the whole wave wait; no extra barrier needed.
        if (tid < 320 && (tid & 63) < 3) {
            int qq = (q + 1 + (tid & 63)) & 3;
            const unsigned int* fp = &xflags[(b * 4 + qq) * 16];
            while (__hip_atomic_load(fp, __ATOMIC_RELAXED, __HIP_MEMORY_SCOPE_AGENT)
                   < (unsigned int)(t + 1)) {}
        }
        asm volatile("" ::: "memory");

        // ---- gather remote payloads (sc1), then LDS writes
        if (tid < 288) {
            int rr = tid / 96;
            int widx = tid - rr * 96;
            int c = (q + 1 + rr) & 3;
            unsigned int v = __hip_atomic_load(&xbuf[((par * NB + b) * 4 + c) * WPB + widx],
                                               __ATOMIC_RELAXED, __HIP_MEMORY_SCOPE_AGENT);
            if (widx < 64) {
                h1w[c * 64 + widx] = v;
            } else {
                int m = widx - 64;
                float f = __uint_as_float(v);
                h2f[32 * c + m] = f;
                float g = __shfl_xor(f, 1, 64);
                if ((m & 1) == 0) h2w[(32 * c + m) >> 1] = pack_h2(f, g);
            }
        }
        // own contributions
        if (s8 == 0) h1w[64 * q + rp] = hp;
        if (ks2 == 0) h2f[R2] = h2v;
        if ((tid & 31) == 0) h2w[16 * q + (tid >> 5)] = pack_h2(h2v, h2vp);

        __syncthreads();   // B3: h1w=h1(t), h2w=h2(t-1), h2f=h2(t-1) complete
    }

    // ================= epilogue =================
    // state: h1w=h1(1023), h2w=h2(1022), h2f=h2(1022)
    // L2(1023):
    {
        float a2 = 0.f;
        #pragma unroll
        for (int r = 0; r < 8; ++r) {
            uint2 H = h1q[ks2 + 16 * r];
            a2 = dot2f(w2r[2 * r + 0], H.x, a2);
            a2 = dot2f(w2r[2 * r + 1], H.y, a2);
        }
        #pragma unroll
        for (int r = 0; r < 2; ++r) {
            uint2 H = h2q[ks2 + 16 * r];
            a2 = dot2f(w3r[2 * r + 0], H.x, a2);
            a2 = dot2f(w3r[2 * r + 1], H.y, a2);
        }
        #pragma unroll
        for (int d = 1; d < 16; d <<= 1) a2 += __shfl_xor(a2, d, 64);
        float h2v = tanh_fast(a2 + bias2);
        if (ks2 == 0)
            __hip_atomic_store(&xbuf[((0 * NB + b) * 4 + q) * WPB + 64 + r2],
                               __float_as_uint(h2v),
                               __ATOMIC_RELAXED, __HIP_MEMORY_SCOPE_AGENT);
        // softmax(1022) -> col 14 (h2f still h2(1022))
        if (tid < 64) softmax_store(h2f, ostage, q, tid, 14);
        __syncthreads();
        if (tid == 0)
            __hip_atomic_store(&xflags[(b * 4 + q) * 16], 1025u,
                               __ATOMIC_RELAXED, __HIP_MEMORY_SCOPE_AGENT);
        if (tid < 128 && (tid & 63) < 3) {
            int qq = (q + 1 + (tid & 63)) & 3;
            const unsigned int* fp = &xflags[(b * 4 + qq) * 16];
            while (__hip_atomic_load(fp, __ATOMIC_RELAXED, __HIP_MEMORY_SCOPE_AGENT)
                   < 1025u) {}
        }
        asm volatile("" ::: "memory");
        if (tid < 96) {
            int rr = tid / 32, m = tid - rr * 32;
            int c = (q + 1 + rr) & 3;
            unsigned int v = __hip_atomic_load(&xbuf[((0 * NB + b) * 4 + c) * WPB + 64 + m],
                                               __ATOMIC_RELAXED, __HIP_MEMORY_SCOPE_AGENT);
            h2f[32 * c + m] = __uint_as_float(v);
        }
        if (ks2 == 0) h2f[R2] = h2v;
        __syncthreads();
        if (tid < 64) softmax_store(h2f, ostage, q, tid, 15);   // softmax(1023)
        __syncthreads();
    }
    // final flush: window t0 = 1008
    if (tid < 128) {
        int row = tid >> 2, seg = tid & 3;
        int t0 = SEQ - 16;
        float4 o;
        o.x = ostage[row][seg * 4 + 0];
        o.y = ostage[row][seg * 4 + 1];
        o.z = ostage[row][seg * 4 + 2];
        o.w = ostage[row][seg * 4 + 3];
        *(float4*)(out + (size_t)(b * NOUT + 32 * q + row) * SEQ + t0 + seg * 4) = o;
    }
}

extern "C" void kernel_launch(void* const* d_in, const int* in_sizes, int n_in,
                              void* d_out, int out_size, void* d_ws, size_t ws_size,
                              hipStream_t stream) {
    const int*   x     = (const int*)d_in[0];
    const float* emb   = (const float*)d_in[1];
    const float* Wih1  = (const float*)d_in[2];
    const float* Whh1  = (const float*)d_in[3];
    const float* bih1  = (const float*)d_in[4];
    const float* bhh1  = (const float*)d_in[5];
    const float* Wih2  = (const float*)d_in[6];
    const float* Whh2  = (const float*)d_in[7];
    const float* bih2  = (const float*)d_in[8];
    const float* bhh2  = (const float*)d_in[9];
    float* out = (float*)d_out;

    unsigned int* whh1T  = (unsigned int*)d_ws;          // 131072 u32
    unsigned int* wih2T  = whh1T + 131072;               // 32768 u32
    unsigned int* whh2T  = wih2T + 32768;                // 8192 u32
    unsigned int* xflags = whh2T + 8192;                 // 4096 u32
    unsigned int* xbuf   = xflags + 4096;                // 49152 u32 (2 par x 64 b x 4 q x 96)
    float* pre1 = (float*)(xbuf + 49152);                // 65536*512 f32

    k_pack<<<672, 256, 0, stream>>>(Whh1, Wih2, Whh2, whh1T, wih2T, whh2T, xflags);

    dim3 gA(65536 / 64, 2);
    k_gemmA<<<gA, 256, 0, stream>>>(x, emb, Wih1, bih1, bhh1, pre1);

    k_scan<<<256, 512, 0, stream>>>(pre1, whh1T, wih2T, whh2T, bih2, bhh2,
                                    xflags, xbuf, out);
}

// Round 4
// 2450.497 us; speedup vs baseline: 4.0297x; 1.2886x over previous
//
#include <hip/hip_runtime.h>
#include <hip/hip_fp16.h>

#define VOCAB 32000
#define EMB   256
#define HID   512
#define NOUT  128
#define SEQ   1024
#define NB    64
#define PPB   80   // packets per block per step: 64 h1-pairs + 16 h2-pairs

typedef _Float16 half2v __attribute__((ext_vector_type(2)));
typedef unsigned long long u64;

__device__ __forceinline__ float dot2f(unsigned int w, unsigned int h, float acc) {
#if __has_builtin(__builtin_amdgcn_fdot2)
    return __builtin_amdgcn_fdot2(__builtin_bit_cast(half2v, w),
                                  __builtin_bit_cast(half2v, h), acc, false);
#else
    half2v a = __builtin_bit_cast(half2v, w);
    half2v b = __builtin_bit_cast(half2v, h);
    acc += (float)a[0] * (float)b[0];
    acc += (float)a[1] * (float)b[1];
    return acc;
#endif
}

__device__ __forceinline__ float tanh_fast(float x) {
    return 1.0f - 2.0f / (__expf(2.0f * x) + 1.0f);
}

__device__ __forceinline__ unsigned int pack_h2(float a, float b) {
    unsigned int lo = (unsigned int)__half_as_ushort(__float2half_rn(a));
    unsigned int hi = (unsigned int)__half_as_ushort(__float2half_rn(b));
    return lo | (hi << 16);
}

__device__ __forceinline__ float f16lo(unsigned int w) {
    return __half2float(__ushort_as_half((unsigned short)(w & 0xffffu)));
}
__device__ __forceinline__ float f16hi(unsigned int w) {
    return __half2float(__ushort_as_half((unsigned short)(w >> 16)));
}

// ---------------------------------------------------------------------------
// Pack weights to f16 pairs, K-major; zero the packet buffer (seq words must
// start at 0 -- d_ws is poisoned 0xAA before every timed launch).
// ---------------------------------------------------------------------------
__global__ void k_pack(const float* __restrict__ Whh1, const float* __restrict__ Wih2,
                       const float* __restrict__ Whh2,
                       unsigned int* __restrict__ whh1T, unsigned int* __restrict__ wih2T,
                       unsigned int* __restrict__ whh2T, unsigned int* __restrict__ xqz) {
    int gid = blockIdx.x * 256 + threadIdx.x;
    if (gid < 81920) xqz[gid] = 0u;   // 2 par x 64 b x 4 q x 80 packets x 2 words
    if (gid < 131072) {
        int p = gid >> 9, n = gid & 511;
        whh1T[gid] = pack_h2(Whh1[n * 512 + 2 * p], Whh1[n * 512 + 2 * p + 1]);
    } else if (gid < 131072 + 32768) {
        int w = gid - 131072;
        int p = w >> 7, j = w & 127;
        wih2T[w] = pack_h2(Wih2[j * 512 + 2 * p], Wih2[j * 512 + 2 * p + 1]);
    } else if (gid < 131072 + 32768 + 8192) {
        int w = gid - 163840;
        int p = w >> 7, j = w & 127;
        whh2T[w] = pack_h2(Whh2[j * 128 + 2 * p], Whh2[j * 128 + 2 * p + 1]);
    }
}

// ---------------------------------------------------------------------------
// pre1 GEMM with embedding gather (unchanged).
// ---------------------------------------------------------------------------
__global__ __launch_bounds__(256, 2) void k_gemmA(const int* __restrict__ x,
                                                  const float* __restrict__ emb,
                                                  const float* __restrict__ W,
                                                  const float* __restrict__ b1,
                                                  const float* __restrict__ b2,
                                                  float* __restrict__ pre1) {
    __shared__ float At[32][64];
    __shared__ float Bt[32][256];
    const int m0 = blockIdx.x * 64;
    const int n0 = blockIdx.y * 256;
    const int tid = threadIdx.x;
    const int tx = tid & 31, ty = tid >> 5;
    float acc[8][8] = {};

    for (int k0 = 0; k0 < EMB; k0 += 32) {
        #pragma unroll
        for (int it = 0; it < 2; ++it) {
            int s = it * 256 + tid;
            int m = s >> 3, kg = s & 7;
            int mg = m0 + m;
            int tok = x[(mg & 63) * SEQ + (mg >> 6)];
            const float4 v = *(const float4*)(emb + (size_t)tok * EMB + k0 + kg * 4);
            At[kg * 4 + 0][m] = v.x; At[kg * 4 + 1][m] = v.y;
            At[kg * 4 + 2][m] = v.z; At[kg * 4 + 3][m] = v.w;
        }
        #pragma unroll
        for (int it = 0; it < 8; ++it) {
            int s = it * 256 + tid;
            int n = s >> 3, kg = s & 7;
            const float4 v = *(const float4*)(W + (size_t)(n0 + n) * EMB + k0 + kg * 4);
            Bt[kg * 4 + 0][n] = v.x; Bt[kg * 4 + 1][n] = v.y;
            Bt[kg * 4 + 2][n] = v.z; Bt[kg * 4 + 3][n] = v.w;
        }
        __syncthreads();
        #pragma unroll 4
        for (int k = 0; k < 32; ++k) {
            const float4 a0 = *(const float4*)&At[k][ty * 8];
            const float4 a1 = *(const float4*)&At[k][ty * 8 + 4];
            const float4 b0v = *(const float4*)&Bt[k][tx * 8];
            const float4 b1v = *(const float4*)&Bt[k][tx * 8 + 4];
            const float av[8] = {a0.x, a0.y, a0.z, a0.w, a1.x, a1.y, a1.z, a1.w};
            const float bv[8] = {b0v.x, b0v.y, b0v.z, b0v.w, b1v.x, b1v.y, b1v.z, b1v.w};
            #pragma unroll
            for (int i = 0; i < 8; ++i)
                #pragma unroll
                for (int j = 0; j < 8; ++j)
                    acc[i][j] = fmaf(av[i], bv[j], acc[i][j]);
        }
        __syncthreads();
    }

    const int nb = n0 + tx * 8;
    float bias[8];
    #pragma unroll
    for (int j = 0; j < 8; ++j) bias[j] = b1[nb + j] + b2[nb + j];
    #pragma unroll
    for (int i = 0; i < 8; ++i) {
        int mg = m0 + ty * 8 + i;
        float* dst = pre1 + (size_t)mg * HID + nb;
        float4 o0 = {acc[i][0] + bias[0], acc[i][1] + bias[1], acc[i][2] + bias[2], acc[i][3] + bias[3]};
        float4 o1 = {acc[i][4] + bias[4], acc[i][5] + bias[5], acc[i][6] + bias[6], acc[i][7] + bias[7]};
        *(float4*)dst = o0;
        *(float4*)(dst + 4) = o1;
    }
}

__device__ __forceinline__ void softmax_store(const float* h2fb, float (*ost)[17],
                                              int q, int tid, int col) {
    // caller guards tid<64 (wave0 fully active)
    float v0 = h2fb[2 * tid], v1 = h2fb[2 * tid + 1];
    float m = fmaxf(v0, v1);
    #pragma unroll
    for (int d = 1; d < 64; d <<= 1) m = fmaxf(m, __shfl_xor(m, d, 64));
    float e0 = __expf(v0 - m), e1 = __expf(v1 - m);
    float s = e0 + e1;
    #pragma unroll
    for (int d = 1; d < 64; d <<= 1) s += __shfl_xor(s, d, 64);
    if (tid >= 16 * q && tid < 16 * q + 16) {
        int rr = 2 * tid - 32 * q;
        float inv = __fdividef(1.0f, s);
        ost[rr][col] = e0 * inv;
        ost[rr + 1][col] = e1 * inv;
    }
}

// ---------------------------------------------------------------------------
// Fused scan v4: 256 blocks = 64 batches x 4 slices, 1 block/CU.
// ONE barrier per step. Flagless exchange: 8B {seq,data} packets via AGENT
// relaxed u64 atomics; consumers spin on the packet itself (poll == gather).
// Phase A (all 8 waves): L1(t), rows 2rp/2rp+1 x k-eighth s8, publish own
//   h1 slice packets (seq=t+1) + ds_write own slice to h1w[p^1].
// Window (no barrier needed -- writers touch only [p^1] buffers):
//   waves 0-3: L2(t-1) (8-way k-split, rotated LDS reads = conflict-free),
//     publish h2(t-1) packed-f16 packets; wave0 then softmax(t-2) from
//     h2f[p]; waves 2-3 then flush a 16-step ostage block every 16 steps.
//   waves 4-7: 240 lanes spin-gather 3 remote payloads (h1 seq>=t+1,
//     h2 seq>=t+1 published mid-window by remotes) -> h1w/h2w/h2f [p^1].
// B3: __syncthreads (drains pre1(t+1) prefetch issued at loop top). p ^= 1.
// Softmax inputs are f16-rounded uniformly in all blocks (consistency).
// ---------------------------------------------------------------------------
__global__ __launch_bounds__(512, 2) void k_scan(
    const float* __restrict__ pre1,
    const unsigned int* __restrict__ whh1T,
    const unsigned int* __restrict__ wih2T,
    const unsigned int* __restrict__ whh2T,
    const float* __restrict__ b_ih2,
    const float* __restrict__ b_hh2,
    u64* xq,
    float* __restrict__ out) {

    __shared__ __align__(16) unsigned int h1w[2][256];
    __shared__ __align__(16) unsigned int h2w[2][64];
    __shared__ float h2f[2][128];
    __shared__ float ostage[2][32][17];

    const int tid = threadIdx.x;
    const int bid = blockIdx.x;
    const int b = bid & 63;
    const int q = bid >> 6;
    const int rp = tid >> 3, s8 = tid & 7;   // L1: rows 2rp,2rp+1; k-eighth s8
    const int R2 = 32 * q + (rp & 31);       // L2 row (tid<256)

    // ---- resident weights
    unsigned int w1r[64], w2r[32], w3r[8];
    #pragma unroll
    for (int r = 0; r < 16; ++r)
        #pragma unroll
        for (int i = 0; i < 2; ++i)
            #pragma unroll
            for (int c = 0; c < 2; ++c)
                w1r[r * 4 + i * 2 + c] =
                    whh1T[(size_t)(2 * (s8 + 8 * r) + c) * 512 + (128 * q + 2 * rp + i)];
    if (tid < 256) {
        #pragma unroll
        for (int i = 0; i < 16; ++i) {
            int u2 = s8 * 16 + ((i + s8) & 15);   // rotated (bank-conflict-free reads)
            w2r[2 * i]     = wih2T[(size_t)(2 * u2) * 128 + R2];
            w2r[2 * i + 1] = wih2T[(size_t)(2 * u2 + 1) * 128 + R2];
        }
        #pragma unroll
        for (int i = 0; i < 4; ++i) {
            w3r[2 * i]     = whh2T[(size_t)(2 * (s8 * 4 + i)) * 128 + R2];
            w3r[2 * i + 1] = whh2T[(size_t)(2 * (s8 * 4 + i) + 1) * 128 + R2];
        }
    }
    const float bias2 = (tid < 256) ? (b_ih2[R2] + b_hh2[R2]) : 0.f;

    // gather lane precompute (tids 256..495)
    const int gv = tid - 256;
    const int grr = gv / 80;
    const int gw = gv - grr * 80;
    const int gc = (q + 1 + grr) & 3;

    if (tid < 256) h1w[0][tid] = 0u;
    if (tid < 64)  { h2w[0][tid] = 0u; h2w[1][tid] = 0u; }
    if (tid < 128) { h2f[0][tid] = 0.f; h2f[1][tid] = 0.f; }
    __syncthreads();

    int p = 0;
    float2 PR = *(const float2*)(pre1 + (size_t)b * HID + 128 * q + 2 * rp);  // pre(0)

    for (int t = 0; t < SEQ; ++t) {
        const int par = t & 1;
        const int pn = p ^ 1;
        const size_t selfbase = (size_t)((par * NB + b) * 4 + q) * PPB;

        // prefetch pre(t+1) -- drained only at B3 (whole window to arrive)
        float2 PRn;
        {
            int tn = (t + 1 < SEQ) ? t + 1 : SEQ - 1;
            PRn = *(const float2*)(pre1 + (size_t)(tn * NB + b) * HID + 128 * q + 2 * rp);
        }

        // ---- phase A: L1(t) -- all waves
        {
            const uint2* h1q = (const uint2*)h1w[p];
            float acc0 = 0.f, acc1 = 0.f;
            #pragma unroll
            for (int r = 0; r < 16; ++r) {
                uint2 H = h1q[s8 + 8 * r];
                acc0 = dot2f(w1r[4 * r + 0], H.x, acc0);
                acc0 = dot2f(w1r[4 * r + 1], H.y, acc0);
                acc1 = dot2f(w1r[4 * r + 2], H.x, acc1);
                acc1 = dot2f(w1r[4 * r + 3], H.y, acc1);
            }
            #pragma unroll
            for (int d = 1; d < 8; d <<= 1) {
                acc0 += __shfl_xor(acc0, d, 64);
                acc1 += __shfl_xor(acc1, d, 64);
            }
            if (s8 == 0) {
                float h0 = tanh_fast(acc0 + PR.x);
                float h1v = tanh_fast(acc1 + PR.y);
                unsigned int hp = pack_h2(h0, h1v);
                __hip_atomic_store(&xq[selfbase + rp], ((u64)(t + 1) << 32) | hp,
                                   __ATOMIC_RELAXED, __HIP_MEMORY_SCOPE_AGENT);
                h1w[pn][64 * q + rp] = hp;
            }
        }

        // ---- window: waves 0-3 = L2(t-1) + softmax(t-2) + flush
        if (tid < 256) {
            if (t > 0) {
                const uint2* h1q = (const uint2*)h1w[p];
                const uint2* h2q = (const uint2*)h2w[p];
                float a2 = 0.f;
                #pragma unroll
                for (int i = 0; i < 16; ++i) {
                    uint2 H = h1q[s8 * 16 + ((i + s8) & 15)];
                    a2 = dot2f(w2r[2 * i], H.x, a2);
                    a2 = dot2f(w2r[2 * i + 1], H.y, a2);
                }
                #pragma unroll
                for (int i = 0; i < 4; ++i) {
                    uint2 H = h2q[s8 * 4 + i];
                    a2 = dot2f(w3r[2 * i], H.x, a2);
                    a2 = dot2f(w3r[2 * i + 1], H.y, a2);
                }
                #pragma unroll
                for (int d = 1; d < 8; d <<= 1) a2 += __shfl_xor(a2, d, 64);
                float h2v = tanh_fast(a2 + bias2);
                float h2pv = __shfl_xor(h2v, 8, 64);   // partner row value
                if (s8 == 0) {
                    unsigned int hu = pack_h2(h2v, h2pv);       // low = own
                    h2f[pn][R2] = f16lo(hu);                    // f16-rounded (uniform)
                    if ((tid & 15) == 0) {
                        h2w[pn][16 * q + (tid >> 4)] = hu;
                        __hip_atomic_store(&xq[selfbase + 64 + (tid >> 4)],
                                           ((u64)(t + 1) << 32) | hu,
                                           __ATOMIC_RELAXED, __HIP_MEMORY_SCOPE_AGENT);
                    }
                }
            }
            if (t >= 2 && tid < 64)
                softmax_store(h2f[p], ostage[((t - 2) >> 4) & 1], q, tid, (t - 2) & 15);
            if ((t & 15) == 2 && t >= 18 && tid >= 128) {
                int v2 = tid - 128, row = v2 >> 2, seg = v2 & 3;
                int t0 = t - 18;
                const float* src = ostage[((t - 18) >> 4) & 1][row];
                float4 o = {src[seg * 4], src[seg * 4 + 1], src[seg * 4 + 2], src[seg * 4 + 3]};
                *(float4*)(out + (size_t)(b * NOUT + 32 * q + row) * SEQ + t0 + seg * 4) = o;
            }
        } else if (gv < 240) {
            // ---- window: waves 4-7 = spin-gather (poll IS the gather)
            if (gw < 64 || t > 0) {
                const u64* gp = &xq[(size_t)((par * NB + b) * 4 + gc) * PPB + gw];
                const unsigned int expect = (unsigned int)(t + 1);
                u64 P;
                do {
                    P = __hip_atomic_load(gp, __ATOMIC_RELAXED, __HIP_MEMORY_SCOPE_AGENT);
                } while ((unsigned int)(P >> 32) < expect);
                unsigned int d = (unsigned int)P;
                if (gw < 64) {
                    h1w[pn][gc * 64 + gw] = d;
                } else {
                    int m = gw - 64;
                    h2w[pn][16 * gc + m] = d;
                    h2f[pn][32 * gc + 2 * m] = f16lo(d);
                    h2f[pn][32 * gc + 2 * m + 1] = f16hi(d);
                }
            }
        }

        __syncthreads();   // B3: h1w[pn]=h1(t), h2w/h2f[pn]=h2(t-1) complete
        p = pn;
        PR = PRn;
    }

    // ================= epilogue =================
    // p = 0 here: h1w[0]=h1(1023), h2w[0]/h2f[0]=h2(1022)
    {
        const int pe = p, pn = p ^ 1;
        if (tid < 256) {   // L2(1023)
            const uint2* h1q = (const uint2*)h1w[pe];
            const uint2* h2q = (const uint2*)h2w[pe];
            float a2 = 0.f;
            #pragma unroll
            for (int i = 0; i < 16; ++i) {
                uint2 H = h1q[s8 * 16 + ((i + s8) & 15)];
                a2 = dot2f(w2r[2 * i], H.x, a2);
                a2 = dot2f(w2r[2 * i + 1], H.y, a2);
            }
            #pragma unroll
            for (int i = 0; i < 4; ++i) {
                uint2 H = h2q[s8 * 4 + i];
                a2 = dot2f(w3r[2 * i], H.x, a2);
                a2 = dot2f(w3r[2 * i + 1], H.y, a2);
            }
            #pragma unroll
            for (int d = 1; d < 8; d <<= 1) a2 += __shfl_xor(a2, d, 64);
            float h2v = tanh_fast(a2 + bias2);
            float h2pv = __shfl_xor(h2v, 8, 64);
            if (s8 == 0) {
                unsigned int hu = pack_h2(h2v, h2pv);
                h2f[pn][R2] = f16lo(hu);
                if ((tid & 15) == 0)
                    __hip_atomic_store(&xq[(size_t)((0 * NB + b) * 4 + q) * PPB + 64 + (tid >> 4)],
                                       ((u64)1025u << 32) | hu,
                                       __ATOMIC_RELAXED, __HIP_MEMORY_SCOPE_AGENT);
            }
        }
        if (tid < 64) softmax_store(h2f[pe], ostage[1], q, tid, 14);   // softmax(1022)
        if (tid >= 256 && gv < 240 && gw >= 64) {
            const u64* gp = &xq[(size_t)((0 * NB + b) * 4 + gc) * PPB + gw];
            u64 P;
            do {
                P = __hip_atomic_load(gp, __ATOMIC_RELAXED, __HIP_MEMORY_SCOPE_AGENT);
            } while ((unsigned int)(P >> 32) < 1025u);
            unsigned int d = (unsigned int)P;
            int m = gw - 64;
            h2f[pn][32 * gc + 2 * m] = f16lo(d);
            h2f[pn][32 * gc + 2 * m + 1] = f16hi(d);
        }
        __syncthreads();
        if (tid < 64) softmax_store(h2f[pn], ostage[1], q, tid, 15);   // softmax(1023)
        __syncthreads();
        if (tid < 128) {   // final flush t0=1008
            int row = tid >> 2, seg = tid & 3;
            const float* src = ostage[1][row];
            float4 o = {src[seg * 4], src[seg * 4 + 1], src[seg * 4 + 2], src[seg * 4 + 3]};
            *(float4*)(out + (size_t)(b * NOUT + 32 * q + row) * SEQ + (SEQ - 16) + seg * 4) = o;
        }
    }
}

extern "C" void kernel_launch(void* const* d_in, const int* in_sizes, int n_in,
                              void* d_out, int out_size, void* d_ws, size_t ws_size,
                              hipStream_t stream) {
    const int*   x     = (const int*)d_in[0];
    const float* emb   = (const float*)d_in[1];
    const float* Wih1  = (const float*)d_in[2];
    const float* Whh1  = (const float*)d_in[3];
    const float* bih1  = (const float*)d_in[4];
    const float* bhh1  = (const float*)d_in[5];
    const float* Wih2  = (const float*)d_in[6];
    const float* Whh2  = (const float*)d_in[7];
    const float* bih2  = (const float*)d_in[8];
    const float* bhh2  = (const float*)d_in[9];
    float* out = (float*)d_out;

    unsigned int* whh1T = (unsigned int*)d_ws;           // 131072 u32
    unsigned int* wih2T = whh1T + 131072;                // 32768 u32
    unsigned int* whh2T = wih2T + 32768;                 // 8192 u32
    unsigned int* xqz   = whh2T + 8192;                  // 81920 u32 (40960 u64 packets)
    u64* xq = (u64*)xqz;
    float* pre1 = (float*)(xqz + 81920);                 // 65536*512 f32

    k_pack<<<672, 256, 0, stream>>>(Whh1, Wih2, Whh2, whh1T, wih2T, whh2T, xqz);

    dim3 gA(65536 / 64, 2);
    k_gemmA<<<gA, 256, 0, stream>>>(x, emb, Wih1, bih1, bhh1, pre1);

    k_scan<<<256, 512, 0, stream>>>(pre1, whh1T, wih2T, whh2T, bih2, bhh2, xq, out);
}